// Round 1
// baseline (2421.738 us; speedup 1.0000x reference)
//
#include <hip/hip_runtime.h>
#include <hip/hip_bf16.h>

// Problem constants
#define BW    4096   // B words
#define TT    30     // T timesteps
#define DIN   512    // D input dim
#define HD    1024   // H hidden
#define VCH   128    // V chars
#define G4    4096   // 4*H

typedef __attribute__((ext_vector_type(8))) __bf16 bf16x8;
typedef __attribute__((ext_vector_type(4))) float  f32x4;

__device__ __forceinline__ ushort f2bf(float f) {
    unsigned u = __float_as_uint(f);
    unsigned r = (u + 0x7fffu + ((u >> 16) & 1u)) >> 16;  // RNE
    return (ushort)r;
}

// ---------------- setup kernels ----------------

// fp32 -> bf16 (vectorized x4)
__global__ __launch_bounds__(256) void cvt_bf16_kernel(const float* __restrict__ in,
                                                       ushort* __restrict__ out, int n4) {
    int i = blockIdx.x * 256 + threadIdx.x;
    if (i >= n4) return;
    float4 v = ((const float4*)in)[i];
    ushort4 o;
    o.x = f2bf(v.x); o.y = f2bf(v.y); o.z = f2bf(v.z); o.w = f2bf(v.w);
    ((ushort4*)out)[i] = o;
}

// h0 -> bf16, c0 -> fp32 ws
__global__ __launch_bounds__(256) void init_hc_kernel(const float* __restrict__ h0,
                                                      const float* __restrict__ c0,
                                                      ushort* __restrict__ hb,
                                                      float* __restrict__ c, int n4) {
    int i = blockIdx.x * 256 + threadIdx.x;
    if (i >= n4) return;
    float4 v = ((const float4*)h0)[i];
    ushort4 o;
    o.x = f2bf(v.x); o.y = f2bf(v.y); o.z = f2bf(v.z); o.w = f2bf(v.w);
    ((ushort4*)hb)[i] = o;
    ((float4*)c)[i] = ((const float4*)c0)[i];
}

// projEmb[c][j] = sum_k emb[c][k]*W_ih[j][k] + b_ih[j] + b_hh[j]
// grid: (16 j-tiles of 256, 16 char-groups of 8), 256 threads
__global__ __launch_bounds__(256) void proj_emb_kernel(const float* __restrict__ emb,
                                                       const float* __restrict__ W_ih,
                                                       const float* __restrict__ b_ih,
                                                       const float* __restrict__ b_hh,
                                                       float* __restrict__ pe) {
    __shared__ float se[8][DIN];
    const int j  = blockIdx.x * 256 + threadIdx.x;
    const int c0 = blockIdx.y * 8;
    for (int i = threadIdx.x; i < 8 * DIN; i += 256)
        se[i >> 9][i & (DIN - 1)] = emb[(size_t)c0 * DIN + i];
    __syncthreads();
    const float* w = W_ih + (size_t)j * DIN;
    float s[8];
#pragma unroll
    for (int cc = 0; cc < 8; ++cc) s[cc] = 0.f;
    for (int k = 0; k < DIN; k += 4) {
        float4 wv = *(const float4*)&w[k];
#pragma unroll
        for (int cc = 0; cc < 8; ++cc)
            s[cc] += se[cc][k] * wv.x + se[cc][k+1] * wv.y + se[cc][k+2] * wv.z + se[cc][k+3] * wv.w;
    }
    const float bias = b_ih[j] + b_hh[j];
#pragma unroll
    for (int cc = 0; cc < 8; ++cc)
        pe[(size_t)(c0 + cc) * G4 + j] = s[cc] + bias;
}

// ---------------- recurrent GEMM: gates = h @ W_hh^T ----------------
// A = h bf16 [4096][1024]; Bt = W_hh bf16 [4096][1024] (row-major [N][K]); C fp32 [4096][4096]
// m97 structure: 128x128 tile, 4 waves (2x2), each wave 64x64 via 4x4 of 16x16x32 MFMA,
// global_load_lds width 16 staging, single LDS buffer, 2 barriers per K-step.
__global__ __launch_bounds__(256) void gemm_gates_kernel(const ushort* __restrict__ A,
                                                         const ushort* __restrict__ Bt,
                                                         float* __restrict__ C) {
    constexpr int K = HD;  // 1024
    __shared__ ushort lA[128 * 32];
    __shared__ ushort lB[128 * 32];
    const int bn = blockIdx.x, bm = blockIdx.y;
    const int t    = threadIdx.x;
    const int w    = t >> 6;
    const int lane = t & 63;
    const int wm = (w >> 1) * 64, wn = (w & 1) * 64;

    f32x4 acc[4][4];
#pragma unroll
    for (int i = 0; i < 4; ++i)
#pragma unroll
        for (int j = 0; j < 4; ++j) acc[i][j] = 0.f;

    const ushort* Ablk = A  + (size_t)bm * 128 * K;
    const ushort* Bblk = Bt + (size_t)bn * 128 * K;

    // staging: lane loads 16B; row = w*16 + lane/4 (+64 for 2nd instr), col = (lane&3)*8
    const int srow = (w << 4) + (lane >> 2);
    const int scol = (lane & 3) << 3;
    // fragment read coords
    const int fr = lane & 15;
    const int fk = (lane >> 4) << 3;

    for (int k0 = 0; k0 < K; k0 += 32) {
        __builtin_amdgcn_global_load_lds(
            (const __attribute__((address_space(1))) void*)(Ablk + (size_t)srow * K + k0 + scol),
            (__attribute__((address_space(3))) void*)(lA + w * 512), 16, 0, 0);
        __builtin_amdgcn_global_load_lds(
            (const __attribute__((address_space(1))) void*)(Ablk + (size_t)(srow + 64) * K + k0 + scol),
            (__attribute__((address_space(3))) void*)(lA + 2048 + w * 512), 16, 0, 0);
        __builtin_amdgcn_global_load_lds(
            (const __attribute__((address_space(1))) void*)(Bblk + (size_t)srow * K + k0 + scol),
            (__attribute__((address_space(3))) void*)(lB + w * 512), 16, 0, 0);
        __builtin_amdgcn_global_load_lds(
            (const __attribute__((address_space(1))) void*)(Bblk + (size_t)(srow + 64) * K + k0 + scol),
            (__attribute__((address_space(3))) void*)(lB + 2048 + w * 512), 16, 0, 0);
        __syncthreads();

        bf16x8 af[4], bfr[4];
#pragma unroll
        for (int i = 0; i < 4; ++i)
            af[i] = *(const bf16x8*)(lA + (wm + i * 16 + fr) * 32 + fk);
#pragma unroll
        for (int j = 0; j < 4; ++j)
            bfr[j] = *(const bf16x8*)(lB + (wn + j * 16 + fr) * 32 + fk);
#pragma unroll
        for (int i = 0; i < 4; ++i)
#pragma unroll
            for (int j = 0; j < 4; ++j)
                acc[i][j] = __builtin_amdgcn_mfma_f32_16x16x32_bf16(af[i], bfr[j], acc[i][j], 0, 0, 0);
        __syncthreads();
    }

    // epilogue: C/D layout col=lane&15, row=(lane>>4)*4+reg
    const int crow0 = bm * 128 + wm + ((lane >> 4) << 2);
    const int ccol0 = bn * 128 + wn + (lane & 15);
#pragma unroll
    for (int i = 0; i < 4; ++i)
#pragma unroll
        for (int j = 0; j < 4; ++j)
#pragma unroll
            for (int r = 0; r < 4; ++r)
                C[(size_t)(crow0 + i * 16 + r) * G4 + (ccol0 + j * 16)] = acc[i][j][r];
}

// ---------------- LSTM cell elementwise ----------------
// gates [B][4H] (i,f,g,o), + projEmb[x[b][t]] gather; updates c fp32, h bf16; writes d_out at last step
__global__ __launch_bounds__(256) void lstm_cell_kernel(const float* __restrict__ gates,
                                                        const float* __restrict__ peAll,
                                                        const int* __restrict__ x,
                                                        int t, int last,
                                                        float* __restrict__ c,
                                                        ushort* __restrict__ hb,
                                                        float* __restrict__ hout) {
    const int idx = blockIdx.x * 256 + threadIdx.x;  // over B*H/4
    const int b = idx >> 8;
    const int h = (idx & 255) << 2;
    const int ch = x[b * TT + t];
    const float* pe = peAll + (size_t)ch * G4;
    const float* gr = gates + (size_t)b * G4;
    float4 gi = *(const float4*)(gr + h);
    float4 gf = *(const float4*)(gr + HD + h);
    float4 gg = *(const float4*)(gr + 2 * HD + h);
    float4 go = *(const float4*)(gr + 3 * HD + h);
    float4 pi = *(const float4*)(pe + h);
    float4 pf = *(const float4*)(pe + HD + h);
    float4 pg = *(const float4*)(pe + 2 * HD + h);
    float4 po = *(const float4*)(pe + 3 * HD + h);
    float4 cv = *(const float4*)(c + (size_t)idx * 4);
    float4 cn, hn;
#define CELL(comp)                                                    \
    {                                                                 \
        float I = 1.f / (1.f + __expf(-(gi.comp + pi.comp)));         \
        float F = 1.f / (1.f + __expf(-(gf.comp + pf.comp)));         \
        float G = tanhf(gg.comp + pg.comp);                           \
        float O = 1.f / (1.f + __expf(-(go.comp + po.comp)));         \
        float cc2 = F * cv.comp + I * G;                              \
        cn.comp = cc2;                                                \
        hn.comp = O * tanhf(cc2);                                     \
    }
    CELL(x) CELL(y) CELL(z) CELL(w)
#undef CELL
    *(float4*)(c + (size_t)idx * 4) = cn;
    ushort4 o;
    o.x = f2bf(hn.x); o.y = f2bf(hn.y); o.z = f2bf(hn.z); o.w = f2bf(hn.w);
    ((ushort4*)hb)[idx] = o;
    if (last) ((float4*)hout)[idx] = hn;
}

// ---------------- launch ----------------
extern "C" void kernel_launch(void* const* d_in, const int* in_sizes, int n_in,
                              void* d_out, int out_size, void* d_ws, size_t ws_size,
                              hipStream_t stream) {
    const int*   x    = (const int*)d_in[0];
    const float* emb  = (const float*)d_in[1];
    const float* W_ih = (const float*)d_in[2];
    const float* W_hh = (const float*)d_in[3];
    const float* b_ih = (const float*)d_in[4];
    const float* b_hh = (const float*)d_in[5];
    const float* h0   = (const float*)d_in[6];
    const float* c0   = (const float*)d_in[7];
    float* out = (float*)d_out;

    char* ws = (char*)d_ws;
    float*  gates = (float*)ws;                                   // 4096*4096*4 = 64 MiB
    ushort* whh   = (ushort*)(ws + (size_t)67108864);             // 8 MiB
    float*  pe    = (float*)(ws + (size_t)(67108864 + 8388608));  // 2 MiB
    ushort* hb    = (ushort*)(ws + (size_t)(67108864 + 8388608 + 2097152));            // 8 MiB
    float*  cbuf  = (float*)(ws + (size_t)(67108864 + 8388608 + 2097152 + 8388608));   // 16 MiB
    // total 102,760,448 bytes

    cvt_bf16_kernel<<<4096, 256, 0, stream>>>(W_hh, whh, (G4 * HD) / 4);
    proj_emb_kernel<<<dim3(16, 16), 256, 0, stream>>>(emb, W_ih, b_ih, b_hh, pe);
    init_hc_kernel<<<4096, 256, 0, stream>>>(h0, c0, hb, cbuf, (BW * HD) / 4);

    for (int t = 0; t < TT; ++t) {
        gemm_gates_kernel<<<dim3(32, 32), 256, 0, stream>>>(hb, whh, gates);
        lstm_cell_kernel<<<4096, 256, 0, stream>>>(gates, pe, x, t, (t == TT - 1) ? 1 : 0,
                                                   cbuf, hb, out);
    }
}

// Round 2
// 2136.867 us; speedup vs baseline: 1.1333x; 1.1333x over previous
//
#include <hip/hip_runtime.h>
#include <hip/hip_bf16.h>

// Problem constants
#define BW    4096   // B words
#define TT    30     // T timesteps
#define DIN   512    // D input dim
#define HD    1024   // H hidden
#define VCH   128    // V chars
#define G4    4096   // 4*H

typedef __attribute__((ext_vector_type(8))) __bf16 bf16x8;
typedef __attribute__((ext_vector_type(4))) float  f32x4;

__device__ __forceinline__ ushort f2bf(float f) {
    unsigned u = __float_as_uint(f);
    unsigned r = (u + 0x7fffu + ((u >> 16) & 1u)) >> 16;  // RNE
    return (ushort)r;
}

__device__ __forceinline__ float sigf(float x) {
    return 1.f / (1.f + __expf(-x));
}
__device__ __forceinline__ float tanhfast(float x) {
    return 2.f / (1.f + __expf(-2.f * x)) - 1.f;
}

// ---------------- setup kernels ----------------

__global__ __launch_bounds__(256) void cvt_bf16_kernel(const float* __restrict__ in,
                                                       ushort* __restrict__ out, int n4) {
    int i = blockIdx.x * 256 + threadIdx.x;
    if (i >= n4) return;
    float4 v = ((const float4*)in)[i];
    ushort4 o;
    o.x = f2bf(v.x); o.y = f2bf(v.y); o.z = f2bf(v.z); o.w = f2bf(v.w);
    ((ushort4*)out)[i] = o;
}

__global__ __launch_bounds__(256) void init_hc_kernel(const float* __restrict__ h0,
                                                      const float* __restrict__ c0,
                                                      ushort* __restrict__ hb,
                                                      float* __restrict__ c, int n4) {
    int i = blockIdx.x * 256 + threadIdx.x;
    if (i >= n4) return;
    float4 v = ((const float4*)h0)[i];
    ushort4 o;
    o.x = f2bf(v.x); o.y = f2bf(v.y); o.z = f2bf(v.z); o.w = f2bf(v.w);
    ((ushort4*)hb)[i] = o;
    ((float4*)c)[i] = ((const float4*)c0)[i];
}

// projEmb[c][j] = sum_k emb[c][k]*W_ih[j][k] + b_ih[j] + b_hh[j]
__global__ __launch_bounds__(256) void proj_emb_kernel(const float* __restrict__ emb,
                                                       const float* __restrict__ W_ih,
                                                       const float* __restrict__ b_ih,
                                                       const float* __restrict__ b_hh,
                                                       float* __restrict__ pe) {
    __shared__ float se[8][DIN];
    const int j  = blockIdx.x * 256 + threadIdx.x;
    const int c0 = blockIdx.y * 8;
    for (int i = threadIdx.x; i < 8 * DIN; i += 256)
        se[i >> 9][i & (DIN - 1)] = emb[(size_t)c0 * DIN + i];
    __syncthreads();
    const float* w = W_ih + (size_t)j * DIN;
    float s[8];
#pragma unroll
    for (int cc = 0; cc < 8; ++cc) s[cc] = 0.f;
    for (int k = 0; k < DIN; k += 4) {
        float4 wv = *(const float4*)&w[k];
#pragma unroll
        for (int cc = 0; cc < 8; ++cc)
            s[cc] += se[cc][k] * wv.x + se[cc][k+1] * wv.y + se[cc][k+2] * wv.z + se[cc][k+3] * wv.w;
    }
    const float bias = b_ih[j] + b_hh[j];
#pragma unroll
    for (int cc = 0; cc < 8; ++cc)
        pe[(size_t)(c0 + cc) * G4 + j] = s[cc] + bias;
}

// ---------------- fused recurrent GEMM + LSTM cell ----------------
// A = h(t-1) bf16 [4096][1024]; Bt = W_hh bf16 [4096][1024] row-major [N][K].
// Block computes a 128x128 tile of h @ W_hh^T, but block-columns are
// PERMUTED so each wave's 64 cols = 16 h-values x all 4 gates:
//   LDS B row r -> W_hh row n(r) = ((r>>4)&3)*1024 + bn*32 + ((r>>6)<<4) + (r&15)
// Within a wave, fragment j == gate (i,f,g,o); the cell is computed in-register.
// LDS chunk swizzle: LDS[r][pos p] holds global 16B-chunk (p ^ (r&3)).
__global__ __launch_bounds__(256) void gemm_cell_kernel(const ushort* __restrict__ A,
                                                        const ushort* __restrict__ Bt,
                                                        const float* __restrict__ peAll,
                                                        const int* __restrict__ x,
                                                        int t, int last,
                                                        float* __restrict__ c,
                                                        ushort* __restrict__ hbN,
                                                        float* __restrict__ hout) {
    constexpr int K = HD;  // 1024
    __shared__ ushort lA[128 * 32];
    __shared__ ushort lB[128 * 32];
    const int bn = blockIdx.x, bm = blockIdx.y;
    const int tid  = threadIdx.x;
    const int w    = tid >> 6;
    const int lane = tid & 63;
    const int wm = (w >> 1) * 64, wn = (w & 1) * 64;

    f32x4 acc[4][4];
#pragma unroll
    for (int i = 0; i < 4; ++i)
#pragma unroll
        for (int j = 0; j < 4; ++j) acc[i][j] = 0.f;

    const ushort* Ablk = A + (size_t)bm * 128 * K;

    // staging: each wave issues 2 A + 2 B global_load_lds of 1024B (16 rows x 64B)
    const int srow = (w << 4) + (lane >> 2);   // LDS row for instr set 1; +64 for set 2
    const int sp   = lane & 3;                 // chunk position in LDS row
    const int sc   = sp ^ (srow & 3);          // swizzled global chunk  ((srow+64)&3 == srow&3)
    const int r2   = srow + 64;
    const int nB1 = (((srow >> 4) & 3) << 10) + bn * 32 + ((srow >> 6) << 4) + (srow & 15);
    const int nB2 = (((r2   >> 4) & 3) << 10) + bn * 32 + ((r2   >> 6) << 4) + (r2   & 15);
    const size_t gA1 = (size_t)srow * K + sc * 8;
    const size_t gA2 = (size_t)r2   * K + sc * 8;
    const size_t gB1 = (size_t)nB1  * K + sc * 8;
    const size_t gB2 = (size_t)nB2  * K + sc * 8;

    // fragment read coords (chunk-swizzled)
    const int fr = lane & 15;
    const int cs = (((lane >> 4) ^ (fr & 3)) << 3);  // element offset of swizzled chunk

    for (int k0 = 0; k0 < K; k0 += 32) {
        __builtin_amdgcn_global_load_lds(
            (const __attribute__((address_space(1))) void*)(Ablk + gA1 + k0),
            (__attribute__((address_space(3))) void*)(lA + w * 512), 16, 0, 0);
        __builtin_amdgcn_global_load_lds(
            (const __attribute__((address_space(1))) void*)(Ablk + gA2 + k0),
            (__attribute__((address_space(3))) void*)(lA + 2048 + w * 512), 16, 0, 0);
        __builtin_amdgcn_global_load_lds(
            (const __attribute__((address_space(1))) void*)(Bt + gB1 + k0),
            (__attribute__((address_space(3))) void*)(lB + w * 512), 16, 0, 0);
        __builtin_amdgcn_global_load_lds(
            (const __attribute__((address_space(1))) void*)(Bt + gB2 + k0),
            (__attribute__((address_space(3))) void*)(lB + 2048 + w * 512), 16, 0, 0);
        __syncthreads();

        bf16x8 af[4], bfr[4];
#pragma unroll
        for (int i = 0; i < 4; ++i)
            af[i] = *(const bf16x8*)(lA + (wm + i * 16 + fr) * 32 + cs);
#pragma unroll
        for (int j = 0; j < 4; ++j)
            bfr[j] = *(const bf16x8*)(lB + (wn + j * 16 + fr) * 32 + cs);
#pragma unroll
        for (int i = 0; i < 4; ++i)
#pragma unroll
            for (int j = 0; j < 4; ++j)
                acc[i][j] = __builtin_amdgcn_mfma_f32_16x16x32_bf16(af[i], bfr[j], acc[i][j], 0, 0, 0);
        __syncthreads();
    }

    // ---- fused LSTM cell epilogue (all in-register; j == gate) ----
    const int h_idx = bn * 32 + ((wn >> 6) << 4) + fr;          // this lane's h column
    const int bbase = bm * 128 + wm + ((lane >> 4) << 2);
#pragma unroll
    for (int i = 0; i < 4; ++i) {
#pragma unroll
        for (int r = 0; r < 4; ++r) {
            const int b = bbase + i * 16 + r;
            const int ch = x[b * TT + t];
            const float* pe = peAll + (size_t)ch * G4 + h_idx;
            float I = acc[i][0][r] + pe[0];
            float F = acc[i][1][r] + pe[HD];
            float G = acc[i][2][r] + pe[2 * HD];
            float O = acc[i][3][r] + pe[3 * HD];
            I = sigf(I); F = sigf(F); O = sigf(O); G = tanhfast(G);
            const size_t off = (size_t)b * HD + h_idx;
            float cn = F * c[off] + I * G;
            float hn = O * tanhfast(cn);
            c[off] = cn;
            hbN[off] = f2bf(hn);
            if (last) hout[off] = hn;
        }
    }
}

// ---------------- launch ----------------
extern "C" void kernel_launch(void* const* d_in, const int* in_sizes, int n_in,
                              void* d_out, int out_size, void* d_ws, size_t ws_size,
                              hipStream_t stream) {
    const int*   x    = (const int*)d_in[0];
    const float* emb  = (const float*)d_in[1];
    const float* W_ih = (const float*)d_in[2];
    const float* W_hh = (const float*)d_in[3];
    const float* b_ih = (const float*)d_in[4];
    const float* b_hh = (const float*)d_in[5];
    const float* h0   = (const float*)d_in[6];
    const float* c0   = (const float*)d_in[7];
    float* out = (float*)d_out;

    char* ws = (char*)d_ws;
    ushort* whh = (ushort*)ws;                                  //  8 MiB
    float*  pe  = (float*)(ws + (size_t)8388608);               //  2 MiB
    ushort* hb0 = (ushort*)(ws + (size_t)(8388608 + 2097152));  //  8 MiB
    ushort* hb1 = (ushort*)(ws + (size_t)(8388608 + 2097152 + 8388608));             // 8 MiB
    float*  cbuf = (float*)(ws + (size_t)(8388608 + 2097152 + 8388608 + 8388608));   // 16 MiB
    // total 42 MiB

    cvt_bf16_kernel<<<4096, 256, 0, stream>>>(W_hh, whh, (G4 * HD) / 4);
    proj_emb_kernel<<<dim3(16, 16), 256, 0, stream>>>(emb, W_ih, b_ih, b_hh, pe);
    init_hc_kernel<<<4096, 256, 0, stream>>>(h0, c0, hb0, cbuf, (BW * HD) / 4);

    ushort* hbuf[2] = {hb0, hb1};
    for (int t = 0; t < TT; ++t) {
        gemm_cell_kernel<<<dim3(32, 32), 256, 0, stream>>>(
            hbuf[t & 1], whh, pe, x, t, (t == TT - 1) ? 1 : 0,
            cbuf, hbuf[(t & 1) ^ 1], out);
    }
}

// Round 3
// 1628.356 us; speedup vs baseline: 1.4872x; 1.3123x over previous
//
#include <hip/hip_runtime.h>
#include <hip/hip_bf16.h>

// Problem constants
#define BW    4096   // B words
#define TT    30     // T timesteps
#define DIN   512    // D input dim
#define HD    1024   // H hidden
#define VCH   128    // V chars
#define G4    4096   // 4*H

typedef __attribute__((ext_vector_type(8))) __bf16 bf16x8;
typedef __attribute__((ext_vector_type(4))) float  f32x4;

__device__ __forceinline__ ushort f2bf(float f) {
    unsigned u = __float_as_uint(f);
    unsigned r = (u + 0x7fffu + ((u >> 16) & 1u)) >> 16;  // RNE
    return (ushort)r;
}
__device__ __forceinline__ float sigf(float x) { return 1.f / (1.f + __expf(-x)); }
__device__ __forceinline__ float tanhfast(float x) { return 2.f / (1.f + __expf(-2.f * x)) - 1.f; }

// ---------------- setup kernels ----------------

__global__ __launch_bounds__(256) void cvt_bf16_kernel(const float* __restrict__ in,
                                                       ushort* __restrict__ out, int n4) {
    int i = blockIdx.x * 256 + threadIdx.x;
    if (i >= n4) return;
    float4 v = ((const float4*)in)[i];
    ushort4 o;
    o.x = f2bf(v.x); o.y = f2bf(v.y); o.z = f2bf(v.z); o.w = f2bf(v.w);
    ((ushort4*)out)[i] = o;
}

__global__ __launch_bounds__(256) void init_hc_kernel(const float* __restrict__ h0,
                                                      const float* __restrict__ c0,
                                                      ushort* __restrict__ hb,
                                                      float* __restrict__ c, int n4) {
    int i = blockIdx.x * 256 + threadIdx.x;
    if (i >= n4) return;
    float4 v = ((const float4*)h0)[i];
    ushort4 o;
    o.x = f2bf(v.x); o.y = f2bf(v.y); o.z = f2bf(v.z); o.w = f2bf(v.w);
    ((ushort4*)hb)[i] = o;
    ((float4*)c)[i] = ((const float4*)c0)[i];
}

// projEmb reordered: pe4[ch][h][gate] (float4 per (ch,h))
// value = sum_k emb[ch][k]*W_ih[g*1024+h][k] + b_ih[j] + b_hh[j]
__global__ __launch_bounds__(256) void proj_emb_kernel(const float* __restrict__ emb,
                                                       const float* __restrict__ W_ih,
                                                       const float* __restrict__ b_ih,
                                                       const float* __restrict__ b_hh,
                                                       float* __restrict__ pe) {
    __shared__ float se[8][DIN];
    const int j  = blockIdx.x * 256 + threadIdx.x;   // gate-major row 0..4095
    const int c0 = blockIdx.y * 8;
    for (int i = threadIdx.x; i < 8 * DIN; i += 256)
        se[i >> 9][i & (DIN - 1)] = emb[(size_t)c0 * DIN + i];
    __syncthreads();
    const float* wv = W_ih + (size_t)j * DIN;
    float s[8];
#pragma unroll
    for (int cc = 0; cc < 8; ++cc) s[cc] = 0.f;
    for (int k = 0; k < DIN; k += 4) {
        float4 w4 = *(const float4*)&wv[k];
#pragma unroll
        for (int cc = 0; cc < 8; ++cc)
            s[cc] += se[cc][k] * w4.x + se[cc][k+1] * w4.y + se[cc][k+2] * w4.z + se[cc][k+3] * w4.w;
    }
    const float bias = b_ih[j] + b_hh[j];
    const int g = j >> 10, h = j & 1023;
#pragma unroll
    for (int cc = 0; cc < 8; ++cc)
        pe[(((size_t)(c0 + cc) * HD + h) << 2) + g] = s[cc] + bias;
}

// ---------------- fused 256^2 8-phase GEMM + LSTM cell ----------------
// gates = h(t-1)[4096x1024] @ W_hh^T with gate-permuted N columns:
//   block col r (0..255) -> W_hh row ((r>>4)&3)*1024 + bn*64 + ((r>>6)<<4) + (r&15)
// => wave (w&3) n-frag n == gate n; lane h_idx = bn*64 + (w&3)*16 + fr.
// LDS: tiles[buf][A/B][half][128*64] bf16, XOR swizzle chunk^=(row&7) on
// ds_read with inverse-swizzled global source for global_load_lds (rule #21).

#define STAGE2(AB, SB, SH, SKT)                                                        \
  {                                                                                    \
    ushort* dst0 = &tiles[((((SB)*2 + (AB))*2 + (SH)) * 8192) + (w*2+0)*512];          \
    ushort* dst1 = dst0 + 512;                                                         \
    const ushort *s0, *s1;                                                             \
    if ((AB) == 0) {                                                                   \
      s0 = A + aOff0 + (size_t)(SH)*131072 + (size_t)(SKT)*64;                         \
      s1 = A + aOff1 + (size_t)(SH)*131072 + (size_t)(SKT)*64;                         \
    } else {                                                                           \
      s0 = Bt + bOff[SH][0] + (size_t)(SKT)*64;                                        \
      s1 = Bt + bOff[SH][1] + (size_t)(SKT)*64;                                        \
    }                                                                                  \
    __builtin_amdgcn_global_load_lds((const __attribute__((address_space(1))) void*)s0,\
        (__attribute__((address_space(3))) void*)dst0, 16, 0, 0);                      \
    __builtin_amdgcn_global_load_lds((const __attribute__((address_space(1))) void*)s1,\
        (__attribute__((address_space(3))) void*)dst1, 16, 0, 0);                      \
  }

#define PHASE(BUF, Q, AB, SB, SH, SKT, VM)                                             \
  {                                                                                    \
    const ushort* aT = &tiles[(((BUF)*2 + 0)*2 + haA) * 8192];                         \
    const ushort* bT = &tiles[(((BUF)*2 + 1)*2 + haB) * 8192];                         \
    if ((Q) == 0) {                                                                    \
      _Pragma("unroll")                                                                \
      for (int n = 0; n < 4; ++n) {                                                    \
        bfr[n][0] = *(const bf16x8*)(bT + hbOff + n*1024 + aoff0);                     \
        bfr[n][1] = *(const bf16x8*)(bT + hbOff + n*1024 + aoff1);                     \
      }                                                                                \
    }                                                                                  \
    bf16x8 a00 = *(const bf16x8*)(aT + (2*(Q)+0)*1024 + aoff0);                        \
    bf16x8 a01 = *(const bf16x8*)(aT + (2*(Q)+0)*1024 + aoff1);                        \
    bf16x8 a10 = *(const bf16x8*)(aT + (2*(Q)+1)*1024 + aoff0);                        \
    bf16x8 a11 = *(const bf16x8*)(aT + (2*(Q)+1)*1024 + aoff1);                        \
    STAGE2(AB, SB, SH, SKT);                                                           \
    __builtin_amdgcn_s_barrier();                                                      \
    asm volatile("s_waitcnt lgkmcnt(0)" ::: "memory");                                 \
    __builtin_amdgcn_s_setprio(1);                                                     \
    _Pragma("unroll")                                                                  \
    for (int n = 0; n < 4; ++n) {                                                      \
      acc[2*(Q)+0][n] = __builtin_amdgcn_mfma_f32_16x16x32_bf16(a00, bfr[n][0], acc[2*(Q)+0][n], 0, 0, 0); \
      acc[2*(Q)+0][n] = __builtin_amdgcn_mfma_f32_16x16x32_bf16(a01, bfr[n][1], acc[2*(Q)+0][n], 0, 0, 0); \
      acc[2*(Q)+1][n] = __builtin_amdgcn_mfma_f32_16x16x32_bf16(a10, bfr[n][0], acc[2*(Q)+1][n], 0, 0, 0); \
      acc[2*(Q)+1][n] = __builtin_amdgcn_mfma_f32_16x16x32_bf16(a11, bfr[n][1], acc[2*(Q)+1][n], 0, 0, 0); \
    }                                                                                  \
    __builtin_amdgcn_s_setprio(0);                                                     \
    if (VM) asm volatile("s_waitcnt vmcnt(4)" ::: "memory");                           \
    __builtin_amdgcn_s_barrier();                                                      \
    asm volatile("" ::: "memory");                                                     \
  }

__global__ __launch_bounds__(512, 2) void gemm_cell_kernel(const ushort* __restrict__ A,
                                                           const ushort* __restrict__ Bt,
                                                           const float* __restrict__ peAll,
                                                           const int* __restrict__ x,
                                                           int t, int last,
                                                           float* __restrict__ c,
                                                           ushort* __restrict__ hbN,
                                                           float* __restrict__ hout) {
    __shared__ ushort tiles[65536];  // 128 KiB: [buf][A/B][half][128*64]

    // XCD-bijective block swizzle (256 % 8 == 0)
    const int orig = blockIdx.x;
    const int wgid = (orig & 7) * 32 + (orig >> 3);
    const int bm = wgid >> 4, bn = wgid & 15;

    const int tid = threadIdx.x;
    const int w = tid >> 6, l = tid & 63;
    const int fr = l & 15, hi = l >> 4;
    const int haA = w >> 2;           // A half this wave reads
    const int haB = (w >> 1) & 1;     // B half this wave reads
    const int hbOff = (w & 1) * 4096; // 64-row offset within B half

    // ---- staging address precompute (inverse-swizzled global source) ----
    const int r0 = (w * 2 + 0) * 8 + (l >> 3), r1 = r0 + 8;
    const int csrc = (l & 7) ^ (l >> 3);
    const size_t aOff0 = (size_t)(bm * 256 + r0) * 1024 + csrc * 8;
    const size_t aOff1 = (size_t)(bm * 256 + r1) * 1024 + csrc * 8;
    size_t bOff[2][2];
#pragma unroll
    for (int half = 0; half < 2; ++half) {
        const int ra = half * 128 + r0, rb = half * 128 + r1;
        const int na = ((ra >> 4) & 3) * 1024 + bn * 64 + ((ra >> 6) << 4) + (ra & 15);
        const int nb = ((rb >> 4) & 3) * 1024 + bn * 64 + ((rb >> 6) << 4) + (rb & 15);
        bOff[half][0] = (size_t)na * 1024 + csrc * 8;
        bOff[half][1] = (size_t)nb * 1024 + csrc * 8;
    }

    // ---- ds_read fragment offsets (swizzled) ----
    const int aoff0 = fr * 64 + ((hi) ^ (fr & 7)) * 8;      // k-sub 0
    const int aoff1 = fr * 64 + ((4 + hi) ^ (fr & 7)) * 8;  // k-sub 1

    f32x4 acc[8][4];
#pragma unroll
    for (int m = 0; m < 8; ++m)
#pragma unroll
        for (int n = 0; n < 4; ++n) acc[m][n] = 0.f;
    bf16x8 bfr[4][2];

    // ---- prologue: A0h0,A0h1,B0h0,B0h1,B1h0,B1h1 ----
    STAGE2(0, 0, 0, 0);
    STAGE2(0, 0, 1, 0);
    STAGE2(1, 0, 0, 0);
    STAGE2(1, 0, 1, 0);
    STAGE2(1, 1, 0, 1);
    STAGE2(1, 1, 1, 1);
    asm volatile("s_waitcnt vmcnt(4)" ::: "memory");
    __builtin_amdgcn_s_barrier();
    asm volatile("" ::: "memory");

    // ---- main loop: 8 iters x 2 K-tiles (K=1024, BK=64) ----
    for (int i = 0; i < 8; ++i) {
        const int k0 = 2 * i;
        PHASE(0, 0, 0, 1, 0, k0 + 1, 0);          // stage A(2i+1)h0 -> buf1
        PHASE(0, 1, 0, 1, 1, k0 + 1, 0);          // stage A(2i+1)h1
        PHASE(0, 2, 1, 0, 0, (k0 + 2) & 15, 0);   // stage B(2i+2)h0 -> buf0
        PHASE(0, 3, 1, 0, 1, (k0 + 2) & 15, 1);   // stage B(2i+2)h1, vmcnt(4)
        PHASE(1, 0, 0, 0, 0, (k0 + 2) & 15, 0);   // stage A(2i+2)h0 -> buf0
        PHASE(1, 1, 0, 0, 1, (k0 + 2) & 15, 0);   // stage A(2i+2)h1
        PHASE(1, 2, 1, 1, 0, (k0 + 3) & 15, 0);   // stage B(2i+3)h0 -> buf1
        PHASE(1, 3, 1, 1, 1, (k0 + 3) & 15, 1);   // stage B(2i+3)h1, vmcnt(4)
    }

    // ---- fused LSTM cell epilogue (n-frag == gate) ----
    const int h_idx = bn * 64 + (w & 3) * 16 + fr;
    const int bbase = bm * 256 + (w >> 2) * 128 + (hi << 2);
    const float4* pe4 = (const float4*)peAll;
#pragma unroll
    for (int m = 0; m < 8; ++m) {
#pragma unroll
        for (int r = 0; r < 4; ++r) {
            const int b = bbase + m * 16 + r;
            const int ch = x[b * TT + t];
            const float4 pv = pe4[(size_t)ch * HD + h_idx];
            float I = sigf(acc[m][0][r] + pv.x);
            float F = sigf(acc[m][1][r] + pv.y);
            float G = tanhfast(acc[m][2][r] + pv.z);
            float O = sigf(acc[m][3][r] + pv.w);
            const size_t off = (size_t)b * HD + h_idx;
            const float cn = F * c[off] + I * G;
            const float hn = O * tanhfast(cn);
            c[off] = cn;
            hbN[off] = f2bf(hn);
            if (last) hout[off] = hn;
        }
    }
}

// ---------------- launch ----------------
extern "C" void kernel_launch(void* const* d_in, const int* in_sizes, int n_in,
                              void* d_out, int out_size, void* d_ws, size_t ws_size,
                              hipStream_t stream) {
    const int*   x    = (const int*)d_in[0];
    const float* emb  = (const float*)d_in[1];
    const float* W_ih = (const float*)d_in[2];
    const float* W_hh = (const float*)d_in[3];
    const float* b_ih = (const float*)d_in[4];
    const float* b_hh = (const float*)d_in[5];
    const float* h0   = (const float*)d_in[6];
    const float* c0   = (const float*)d_in[7];
    float* out = (float*)d_out;

    char* ws = (char*)d_ws;
    ushort* whh = (ushort*)ws;                                  //  8 MiB
    float*  pe  = (float*)(ws + (size_t)8388608);               //  2 MiB (pe4 layout)
    ushort* hb0 = (ushort*)(ws + (size_t)(8388608 + 2097152));  //  8 MiB
    ushort* hb1 = (ushort*)(ws + (size_t)(8388608 + 2097152 + 8388608));             // 8 MiB
    float*  cbuf = (float*)(ws + (size_t)(8388608 + 2097152 + 8388608 + 8388608));   // 16 MiB

    cvt_bf16_kernel<<<4096, 256, 0, stream>>>(W_hh, whh, (G4 * HD) / 4);
    proj_emb_kernel<<<dim3(16, 16), 256, 0, stream>>>(emb, W_ih, b_ih, b_hh, pe);
    init_hc_kernel<<<4096, 256, 0, stream>>>(h0, c0, hb0, cbuf, (BW * HD) / 4);

    ushort* hbuf[2] = {hb0, hb1};
    for (int t = 0; t < TT; ++t) {
        gemm_cell_kernel<<<256, 512, 0, stream>>>(
            hbuf[t & 1], whh, pe, x, t, (t == TT - 1) ? 1 : 0,
            cbuf, hbuf[(t & 1) ^ 1], out);
    }
}